// Round 4
// baseline (5433.584 us; speedup 1.0000x reference)
//
#include <hip/hip_runtime.h>

typedef __attribute__((ext_vector_type(8))) short short8;
typedef __attribute__((ext_vector_type(4))) float floatx4;

#define T_STEPS 1024
#define BATCH   256
#define INSZ    128
#define HID     512
#define OUTSZ   32

#define MFMA16(a,b,c) __builtin_amdgcn_mfma_f32_16x16x32_bf16((a),(b),(c),0,0,0)

// bf16 helpers (RNE)
static __device__ __forceinline__ short f2bf(float f) {
  unsigned int u = __float_as_uint(f);
  u += 0x7fffu + ((u >> 16) & 1u);
  return (short)(u >> 16);
}
static __device__ __forceinline__ float bf2f(short s) {
  return __uint_as_float(((unsigned int)(unsigned short)s) << 16);
}
// packed f32->bf16 (RNE), 1 inst for 2 values
static __device__ __forceinline__ unsigned cvt_pk_bf16(float lo, float hi) {
  unsigned r;
  asm("v_cvt_pk_bf16_f32 %0, %1, %2" : "=v"(r) : "v"(lo), "v"(hi));
  return r;
}

// ---------------------------------------------------------------------------
// Pack weights into MFMA B-fragment-linear bf16 layouts.
// B-frag for 16x16x32: lane = ((k%32)/8)*16 + (n%16), elem j = k%8.
// frag id = kt*NT + nt ; pos = (frag*64 + lane)*8 + j
// ---------------------------------------------------------------------------
__global__ __launch_bounds__(256) void pack_kernel(
    const float* __restrict__ W_rec, const float* __restrict__ W_in,
    const float* __restrict__ W_out,
    short* __restrict__ w_rec_p, short* __restrict__ w_in_p,
    short* __restrict__ w_out_p) {
  int i = blockIdx.x * 256 + threadIdx.x;  // 0..262143
  {
    // W_rec[n][k] used as B[k][n]  (h @ W_rec^T)
    int n = i >> 9, k = i & 511;
    int pos = ((((k >> 5) * 32 + (n >> 4)) * 64 + ((k >> 3) & 3) * 16 + (n & 15)) << 3) + (k & 7);
    w_rec_p[pos] = f2bf(W_rec[i]);
  }
  if (i < INSZ * HID) {
    int k = i >> 9, n = i & 511;  // W_in[k][n] used as B[k][n]
    int pos = ((((k >> 5) * 32 + (n >> 4)) * 64 + ((k >> 3) & 3) * 16 + (n & 15)) << 3) + (k & 7);
    w_in_p[pos] = f2bf(W_in[i]);
  }
  if (i < HID * OUTSZ) {
    int k = i >> 5, o = i & 31;   // W_out[k][o] used as B[k][o], NT=2
    int pos = ((((k >> 5) * 2 + (o >> 4)) * 64 + ((k >> 3) & 3) * 16 + (o & 15)) << 3) + (k & 7);
    w_out_p[pos] = f2bf(W_out[i]);
  }
}

// ---------------------------------------------------------------------------
// Fused kernel (1024 threads = 16 waves), one launch per chunk phase c:
//   blocks [0,16)         : scan of chunk c       (16 batch rows per block)
//   blocks [16, 16+chunk) : xproj of chunk c+1    (one timestep per block)
//   remaining chunk blocks: out GEMM of chunk c-1 (one timestep per block)
//
// Scan register budget IS the design constraint: previous 8-wave versions
// needed 192 VGPRs of resident W_rec but the allocator refused to budget
// beyond 128 (VGPR_Count=128 across 3 rounds), re-filling weights from L2
// every timestep (~6000 cy/step). Here each wave owns only 32 columns:
// wreg = 12kt x 2nt x 4 = 96 VGPRs, total demand ~128 -> truly resident
// under the hard cap from __launch_bounds__(1024, 4). 4 waves/SIMD also
// doubles latency hiding. LDS: 4 ktiles (128KB) + 2x16KB h = 160KB.
// ---------------------------------------------------------------------------
__global__ __launch_bounds__(1024, 4) void fused_kernel(
    const float* __restrict__ inputs,
    const short* __restrict__ w_rec_p, const short* __restrict__ w_in_p,
    const short* __restrict__ w_out_p,
    const float* __restrict__ b_rec, const float* __restrict__ b_out,
    short* __restrict__ xp0, short* __restrict__ xp1,
    short* __restrict__ hs0, short* __restrict__ hs1,
    float* __restrict__ h_carry, float* __restrict__ out,
    int c, int chunk, int nchunks) {
  __shared__ __align__(16) char smem[163840];
  const int tid  = threadIdx.x;
  const int wave = tid >> 6, lane = tid & 63;
  const int l15  = lane & 15, q = lane >> 4;

  const int sb = (c >= 0 && c < nchunks) ? 16 : 0;
  const int nx = (c + 1 < nchunks) ? chunk : 0;
  const int bid = blockIdx.x;

  if (bid < sb) {
    // ================= scan role: chunk c, 16 batch rows per block ==========
    short* w_lds = (short*)smem;               // 128 KB: W_rec ktiles 12..15
    short* hbuf  = (short*)(smem + 131072);    // 2 x 16KB double-buffered h
    const short* xp = (c & 1) ? xp1 : xp0;
    short* hs = (c & 1) ? hs1 : hs0;
    const int slab = bid * 16;
    const int first = (c == 0);
    const int n0 = 2 * wave;                   // wave owns ntiles n0, n0+1

    // resident weight fragments, ktiles 0..11, 2 ntiles per wave (96 VGPR)
    short8 wreg[12][2];
    #pragma unroll
    for (int kt = 0; kt < 12; ++kt)
      #pragma unroll
      for (int i = 0; i < 2; ++i)
        wreg[kt][i] = *(const short8*)(w_rec_p + (((kt * 32 + n0 + i) * 64 + lane) << 3));

    // ktiles 12..15 -> LDS (frag-linear region contiguous in w_rec_p)
    for (int e = tid * 8; e < 4 * 32 * 512; e += 1024 * 8)
      *(short8*)(w_lds + e) = *(const short8*)(w_rec_p + 12 * 32 * 512 + e);

    // carried state -> fp32 regs + swizzled bf16 LDS (buffer 0)
    float hold[2][4];
    #pragma unroll
    for (int i = 0; i < 2; ++i) {
      int col = wave * 32 + i * 16 + l15;
      int ck = col >> 3, cl = col & 7;
      #pragma unroll
      for (int r = 0; r < 4; ++r) {
        int row = q * 4 + r;
        float v = 0.f;
        if (!first) v = h_carry[(size_t)(slab + row) * HID + col];
        hold[i][r] = v;
        hbuf[row * 512 + ((ck ^ row) << 3) + cl] = f2bf(v);
      }
    }

    const float alpha = (float)(0.1 / 100.0);
    const float onem  = (float)(1.0 - 0.1 / 100.0);

    __syncthreads();

    int p = 0;
    for (int t = 0; t < chunk; ++t) {
      const short* hb = hbuf + p * (16 * 512);        // h after step t-1
      short* hnb = hbuf + (p ^ 1) * (16 * 512);       // will hold step-t result

      // issue xp[t] load early; consumed after the MFMA loop (latency covered)
      uint2 xq[2];
      #pragma unroll
      for (int i = 0; i < 2; ++i)
        xq[i] = *(const uint2*)(xp + ((((size_t)t * 16 + bid) * 32 + n0 + i) * 64 + lane) * 4);

      // store hs[t-1] from stable buffer hb (overlaps with MFMA)
      if (t > 0) {
        short8 v0 = *(const short8*)(hb + wave * 512 + ((lane ^ wave) << 3));
        *(short8*)(hs + ((size_t)(t - 1) * BATCH + slab) * HID + tid * 8) = v0;
      }

      floatx4 acc[2];
      acc[0] = (floatx4){0.f, 0.f, 0.f, 0.f};
      acc[1] = (floatx4){0.f, 0.f, 0.f, 0.f};

      // MFMA: h @ W_rec^T, ktiles 0..11 from regs, 12..15 from LDS
      #pragma unroll
      for (int kt = 0; kt < 12; ++kt) {
        short8 afr = *(const short8*)(hb + l15 * 512 + (((kt * 4 + q) ^ l15) << 3));
        acc[0] = MFMA16(afr, wreg[kt][0], acc[0]);
        acc[1] = MFMA16(afr, wreg[kt][1], acc[1]);
      }
      #pragma unroll
      for (int kt = 12; kt < 16; ++kt) {
        short8 afr = *(const short8*)(hb + l15 * 512 + (((kt * 4 + q) ^ l15) << 3));
        #pragma unroll
        for (int i = 0; i < 2; ++i) {
          short8 bfr = *(const short8*)(w_lds + (((kt - 12) * 32 + n0 + i) << 9) + lane * 8);
          acc[i] = MFMA16(afr, bfr, acc[i]);
        }
      }

      // epilogue: pre = acc + xp; CTRNN update in fp32; bf16 h -> other buffer
      #pragma unroll
      for (int i = 0; i < 2; ++i) {
        int col = wave * 32 + i * 16 + l15;
        int ck = col >> 3, cl = col & 7;
        float x0 = bf2f((short)(xq[i].x & 0xffffu));
        float x1 = bf2f((short)(xq[i].x >> 16));
        float x2 = bf2f((short)(xq[i].y & 0xffffu));
        float x3 = bf2f((short)(xq[i].y >> 16));
        float h0 = onem * hold[i][0] + alpha * fmaxf(acc[i][0] + x0, 0.f);
        float h1 = onem * hold[i][1] + alpha * fmaxf(acc[i][1] + x1, 0.f);
        float h2 = onem * hold[i][2] + alpha * fmaxf(acc[i][2] + x2, 0.f);
        float h3 = onem * hold[i][3] + alpha * fmaxf(acc[i][3] + x3, 0.f);
        hold[i][0] = h0; hold[i][1] = h1; hold[i][2] = h2; hold[i][3] = h3;
        unsigned u01 = cvt_pk_bf16(h0, h1);
        unsigned u23 = cvt_pk_bf16(h2, h3);
        int r0 = q * 4;
        hnb[(r0 + 0) * 512 + ((ck ^ (r0 + 0)) << 3) + cl] = (short)(u01 & 0xffffu);
        hnb[(r0 + 1) * 512 + ((ck ^ (r0 + 1)) << 3) + cl] = (short)(u01 >> 16);
        hnb[(r0 + 2) * 512 + ((ck ^ (r0 + 2)) << 3) + cl] = (short)(u23 & 0xffffu);
        hnb[(r0 + 3) * 512 + ((ck ^ (r0 + 3)) << 3) + cl] = (short)(u23 >> 16);
      }
      __syncthreads();  // single barrier per step (write buf != read buf)
      p ^= 1;
    }

    // tail: hs[chunk-1] + fp32 carry
    {
      const short* hb = hbuf + p * (16 * 512);
      short8 v0 = *(const short8*)(hb + wave * 512 + ((lane ^ wave) << 3));
      *(short8*)(hs + ((size_t)(chunk - 1) * BATCH + slab) * HID + tid * 8) = v0;
    }
    #pragma unroll
    for (int i = 0; i < 2; ++i) {
      int col = wave * 32 + i * 16 + l15;
      #pragma unroll
      for (int r = 0; r < 4; ++r)
        h_carry[(size_t)(slab + q * 4 + r) * HID + col] = hold[i][r];
    }

  } else if (bid - sb < nx) {
    // ================= xproj role: one timestep of chunk c+1 ================
    const int tt = bid - sb;
    const int cc = c + 1;
    short* xpw = (cc & 1) ? xp1 : xp0;
    const int t_abs = cc * chunk + tt;
    const int n0 = 2 * wave;  // 16 waves x 2 ntiles = 512 cols

    short8 bfr[2][4];
    #pragma unroll
    for (int i = 0; i < 2; ++i)
      #pragma unroll
      for (int kt = 0; kt < 4; ++kt)
        bfr[i][kt] = *(const short8*)(w_in_p + (((kt * 32 + n0 + i) * 64 + lane) << 3));
    float brv[2] = { b_rec[(n0 + 0) * 16 + l15], b_rec[(n0 + 1) * 16 + l15] };

    for (int it = 0; it < 16; ++it) {
      const float* arow = inputs + ((size_t)t_abs * BATCH + it * 16 + l15) * INSZ + q * 8;
      short8 afr[4];
      #pragma unroll
      for (int kt = 0; kt < 4; ++kt) {
        short8 s;
        #pragma unroll
        for (int j = 0; j < 4; ++j) {
          unsigned u = cvt_pk_bf16(arow[kt * 32 + 2 * j], arow[kt * 32 + 2 * j + 1]);
          s[2 * j] = (short)(u & 0xffffu);
          s[2 * j + 1] = (short)(u >> 16);
        }
        afr[kt] = s;
      }
      floatx4 acc[2];
      acc[0] = (floatx4){0.f, 0.f, 0.f, 0.f};
      acc[1] = (floatx4){0.f, 0.f, 0.f, 0.f};
      #pragma unroll
      for (int kt = 0; kt < 4; ++kt) {
        acc[0] = MFMA16(afr[kt], bfr[0][kt], acc[0]);
        acc[1] = MFMA16(afr[kt], bfr[1][kt], acc[1]);
      }
      // store (acc + b_rec) as bf16 in fragment-linear layout: 8B/thread/nt
      #pragma unroll
      for (int i = 0; i < 2; ++i) {
        unsigned u01 = cvt_pk_bf16(acc[i][0] + brv[i], acc[i][1] + brv[i]);
        unsigned u23 = cvt_pk_bf16(acc[i][2] + brv[i], acc[i][3] + brv[i]);
        uint2 u; u.x = u01; u.y = u23;
        *(uint2*)(xpw + ((((size_t)tt * 16 + it) * 32 + n0 + i) * 64 + lane) * 4) = u;
      }
    }

  } else {
    // ================= out role: one timestep of chunk c-1 ==================
    if (tid >= 512) return;  // 8 waves; wave-private LDS tiles (no barrier)
    const int tt = bid - sb - nx;
    const int cc = c - 1;
    const short* hsr = (cc & 1) ? hs1 : hs0;
    short* al = (short*)smem + wave * (16 * 520);  // wave-private padded tile

    float bov[2] = { b_out[l15], b_out[16 + l15] };

    #pragma unroll
    for (int itm = 0; itm < 2; ++itm) {
      int mt = wave * 2 + itm;  // 16-row group within the timestep
      const short* src = hsr + ((size_t)tt * BATCH + mt * 16) * HID;
      #pragma unroll
      for (int r = 0; r < 16; ++r)
        *(short8*)(al + r * 520 + lane * 8) = *(const short8*)(src + r * 512 + lane * 8);
      // wave-private tile: in-wave DS ordering suffices, no barrier

      floatx4 acc2[2];
      acc2[0] = (floatx4){0.f, 0.f, 0.f, 0.f};
      acc2[1] = (floatx4){0.f, 0.f, 0.f, 0.f};
      #pragma unroll
      for (int kt = 0; kt < 16; ++kt) {
        short8 afr = *(const short8*)(al + l15 * 520 + kt * 32 + q * 8);
        // W_out fragments loaded in-loop (L1/L2-hot, keeps register cap safe)
        short8 b0 = *(const short8*)(w_out_p + (((kt * 2 + 0) * 64 + lane) << 3));
        short8 b1 = *(const short8*)(w_out_p + (((kt * 2 + 1) * 64 + lane) << 3));
        acc2[0] = MFMA16(afr, b0, acc2[0]);
        acc2[1] = MFMA16(afr, b1, acc2[1]);
      }
      float* outp = out + ((size_t)(cc * chunk + tt) * BATCH + mt * 16) * OUTSZ;
      #pragma unroll
      for (int ot = 0; ot < 2; ++ot)
        #pragma unroll
        for (int r = 0; r < 4; ++r)
          outp[(size_t)(q * 4 + r) * OUTSZ + ot * 16 + l15] = acc2[ot][r] + bov[ot];
    }
  }
}

// ---------------------------------------------------------------------------
extern "C" void kernel_launch(void* const* d_in, const int* in_sizes, int n_in,
                              void* d_out, int out_size, void* d_ws, size_t ws_size,
                              hipStream_t stream) {
  const float* inputs = (const float*)d_in[0];  // [1024,256,128]
  const float* W_rec  = (const float*)d_in[1];  // [512,512]
  const float* W_in   = (const float*)d_in[2];  // [128,512]
  const float* b_rec  = (const float*)d_in[3];  // [512]
  const float* W_out  = (const float*)d_in[4];  // [512,32]
  const float* b_out  = (const float*)d_in[5];  // [32]
  float* out = (float*)d_out;                   // [1024,256,32]

  char* ws = (char*)d_ws;
  // fixed region (< 2 MB): packed weights + fp32 h carry
  short* w_rec_p = (short*)(ws);                       // 512 KB
  short* w_in_p  = (short*)(ws + 524288);              // 128 KB
  short* w_out_p = (short*)(ws + 655360);              //  32 KB
  float* h_carry = (float*)(ws + 688128);              // 512 KB
  const size_t fixed_end = 2u << 20;                   // 2 MB

  // double-buffered xp + hs: 4 buffers of chunk*256KB each -> 1 MB per step
  const size_t per_step = (size_t)BATCH * HID * 2 * 4;
  int chunk = T_STEPS;
  while (chunk > 1 && fixed_end + (size_t)chunk * per_step > ws_size) chunk >>= 1;
  if (fixed_end + (size_t)chunk * per_step > ws_size) return;  // ws too small
  const int nchunks = T_STEPS / chunk;

  const size_t buf = (size_t)chunk * BATCH * HID * 2;  // bytes per buffer
  short* xp0 = (short*)(ws + fixed_end);
  short* xp1 = (short*)(ws + fixed_end + buf);
  short* hs0 = (short*)(ws + fixed_end + 2 * buf);
  short* hs1 = (short*)(ws + fixed_end + 3 * buf);

  pack_kernel<<<1024, 256, 0, stream>>>(W_rec, W_in, W_out, w_rec_p, w_in_p, w_out_p);

  for (int c = -1; c <= nchunks; ++c) {
    int sb = (c >= 0 && c < nchunks) ? 16 : 0;
    int nx = (c + 1 >= 0 && c + 1 < nchunks) ? chunk : 0;
    int no = (c - 1 >= 0 && c - 1 < nchunks) ? chunk : 0;
    int grid = sb + nx + no;
    if (!grid) continue;
    fused_kernel<<<grid, 1024, 0, stream>>>(inputs, w_rec_p, w_in_p, w_out_p,
        b_rec, b_out, xp0, xp1, hs0, hs1, h_carry, out, c, chunk, nchunks);
  }
}

// Round 5
// 4936.736 us; speedup vs baseline: 1.1006x; 1.1006x over previous
//
#include <hip/hip_runtime.h>

typedef __attribute__((ext_vector_type(8))) short short8;
typedef __attribute__((ext_vector_type(4))) float floatx4;

#define T_STEPS 1024
#define BATCH   256
#define INSZ    128
#define HID     512
#define OUTSZ   32

#define MFMA16(a,b,c) __builtin_amdgcn_mfma_f32_16x16x32_bf16((a),(b),(c),0,0,0)

// bf16 helpers (RNE)
static __device__ __forceinline__ short f2bf(float f) {
  unsigned int u = __float_as_uint(f);
  u += 0x7fffu + ((u >> 16) & 1u);
  return (short)(u >> 16);
}
static __device__ __forceinline__ float bf2f(short s) {
  return __uint_as_float(((unsigned int)(unsigned short)s) << 16);
}
// packed f32->bf16 (RNE), 1 inst for 2 values
static __device__ __forceinline__ unsigned cvt_pk_bf16(float lo, float hi) {
  unsigned r;
  asm("v_cvt_pk_bf16_f32 %0, %1, %2" : "=v"(r) : "v"(lo), "v"(hi));
  return r;
}

// ---------------------------------------------------------------------------
// Pack weights into MFMA B-fragment-linear bf16 layouts.
// B-frag for 16x16x32: lane = ((k%32)/8)*16 + (n%16), elem j = k%8.
// frag id = kt*NT + nt ; pos = (frag*64 + lane)*8 + j
// ---------------------------------------------------------------------------
__global__ __launch_bounds__(256) void pack_kernel(
    const float* __restrict__ W_rec, const float* __restrict__ W_in,
    const float* __restrict__ W_out,
    short* __restrict__ w_rec_p, short* __restrict__ w_in_p,
    short* __restrict__ w_out_p) {
  int i = blockIdx.x * 256 + threadIdx.x;  // 0..262143
  {
    // W_rec[n][k] used as B[k][n]  (h @ W_rec^T)
    int n = i >> 9, k = i & 511;
    int pos = ((((k >> 5) * 32 + (n >> 4)) * 64 + ((k >> 3) & 3) * 16 + (n & 15)) << 3) + (k & 7);
    w_rec_p[pos] = f2bf(W_rec[i]);
  }
  if (i < INSZ * HID) {
    int k = i >> 9, n = i & 511;  // W_in[k][n] used as B[k][n]
    int pos = ((((k >> 5) * 32 + (n >> 4)) * 64 + ((k >> 3) & 3) * 16 + (n & 15)) << 3) + (k & 7);
    w_in_p[pos] = f2bf(W_in[i]);
  }
  if (i < HID * OUTSZ) {
    int k = i >> 5, o = i & 31;   // W_out[k][o] used as B[k][o], NT=2
    int pos = ((((k >> 5) * 2 + (o >> 4)) * 64 + ((k >> 3) & 3) * 16 + (o & 15)) << 3) + (k & 7);
    w_out_p[pos] = f2bf(W_out[i]);
  }
}

// ---------------------------------------------------------------------------
// Fused kernel (512 threads = 8 waves), one launch per chunk phase c:
//   blocks [0,16)         : scan of chunk c       (16 batch rows per block)
//   blocks [16, 16+chunk) : xproj of chunk c+1    (one timestep per block)
//   remaining chunk blocks: out GEMM of chunk c-1 (one timestep per block)
//
// W_rec residency via AGPRs: the allocator consistently budgets only 128
// arch VGPRs (observed across 4 rounds regardless of launch-bounds /
// waves_per_eu attributes), so a 192-reg wreg tile in VGPRs gets re-loaded
// from L2 every timestep (~3600 cy/step — the measured scan bottleneck).
// gfx950 MFMA reads the B operand directly from AGPRs (unified file, AV
// operand class), and the "+a" asm pins below force wreg into the AGPR
// class: 192 AGPR + ~60 arch VGPR = ~250 total, within the 2-waves/EU cap
// that the 160KB LDS already imposes. Copies (v_accvgpr_write) happen once.
// ---------------------------------------------------------------------------
__global__
__attribute__((amdgpu_flat_work_group_size(512, 512)))
__attribute__((amdgpu_waves_per_eu(2, 2)))
void fused_kernel(
    const float* __restrict__ inputs,
    const short* __restrict__ w_rec_p, const short* __restrict__ w_in_p,
    const short* __restrict__ w_out_p,
    const float* __restrict__ b_rec, const float* __restrict__ b_out,
    short* __restrict__ xp0, short* __restrict__ xp1,
    short* __restrict__ hs0, short* __restrict__ hs1,
    float* __restrict__ h_carry, float* __restrict__ out,
    int c, int chunk, int nchunks) {
  __shared__ __align__(16) char smem[163840];  // union: scan 160K / out 8*16640
  const int tid  = threadIdx.x;
  const int wave = tid >> 6, lane = tid & 63;
  const int l15  = lane & 15, q = lane >> 4;

  const int sb = (c >= 0 && c < nchunks) ? 16 : 0;
  const int nx = (c + 1 < nchunks) ? chunk : 0;
  const int bid = blockIdx.x;

  if (bid < sb) {
    // ================= scan role: chunk c, 16 batch rows per block ==========
    short* w_lds = (short*)smem;               // 128 KB: W_rec ktiles 12..15
    short* hbuf  = (short*)(smem + 131072);    // 2 x 16KB double-buffered h
    const short* xp = (c & 1) ? xp1 : xp0;
    short* hs = (c & 1) ? hs1 : hs0;
    const int slab = bid * 16;
    const int first = (c == 0);

    // resident weight fragments, ktiles 0..11 (wave owns cols [wave*64,+64))
    short8 wreg[12][4];
    #pragma unroll
    for (int kt = 0; kt < 12; ++kt)
      #pragma unroll
      for (int nt = 0; nt < 4; ++nt)
        wreg[kt][nt] = *(const short8*)(w_rec_p + (((kt * 32 + wave * 4 + nt) * 64 + lane) << 3));

    // force the W tile into the AGPR class (MFMA consumes B from AGPR in
    // place; arch-VGPR pressure drops under the allocator's 128 budget)
    #pragma unroll
    for (int kt = 0; kt < 12; ++kt)
      #pragma unroll
      for (int nt = 0; nt < 4; ++nt)
        asm volatile("" : "+a"(wreg[kt][nt]));

    // ktiles 12..15 -> LDS (frag-linear region contiguous in w_rec_p)
    for (int e = tid * 8; e < 4 * 32 * 512; e += 512 * 8)
      *(short8*)(w_lds + e) = *(const short8*)(w_rec_p + 12 * 32 * 512 + e);

    // carried state -> fp32 regs + swizzled bf16 LDS (buffer 0)
    float hold[4][4];
    #pragma unroll
    for (int nt = 0; nt < 4; ++nt) {
      int col = wave * 64 + nt * 16 + l15;
      int ck = col >> 3, cl = col & 7;
      #pragma unroll
      for (int r = 0; r < 4; ++r) {
        int row = q * 4 + r;
        float v = 0.f;
        if (!first) v = h_carry[(size_t)(slab + row) * HID + col];
        hold[nt][r] = v;
        hbuf[row * 512 + ((ck ^ row) << 3) + cl] = f2bf(v);
      }
    }

    const float alpha = (float)(0.1 / 100.0);
    const float onem  = (float)(1.0 - 0.1 / 100.0);

    __syncthreads();

    int p = 0;
    for (int t = 0; t < chunk; ++t) {
      const short* hb = hbuf + p * (16 * 512);        // state h_t
      short* hnb = hbuf + (p ^ 1) * (16 * 512);       // will hold h_{t+1}

      // issue xp[t] load early; consumed in the epilogue (covered by MFMAs)
      uint2 xq[4];
      #pragma unroll
      for (int nt = 0; nt < 4; ++nt)
        xq[nt] = *(const uint2*)(xp + ((((size_t)t * 16 + bid) * 32 + wave * 4 + nt) * 64 + lane) * 4);

      // store hs[t-1] from stable buffer hb (overlaps with MFMA)
      if (t > 0) {
        int e = tid * 16;
        int row = e >> 9, c0 = (e & 511) >> 3;
        short8 v0 = *(const short8*)(hb + row * 512 + (((c0    ) ^ row) << 3));
        short8 v1 = *(const short8*)(hb + row * 512 + (((c0 + 1) ^ row) << 3));
        short* dst = hs + ((size_t)(t - 1) * BATCH + slab) * HID + e;
        *(short8*)(dst) = v0;
        *(short8*)(dst + 8) = v1;
      }

      floatx4 acc[4];
      #pragma unroll
      for (int nt = 0; nt < 4; ++nt) acc[nt] = (floatx4){0.f, 0.f, 0.f, 0.f};

      // MFMA: h_t @ W_rec^T, ktiles 0..11 from AGPRs, 12..15 from LDS
      #pragma unroll
      for (int kt = 0; kt < 12; ++kt) {
        short8 afr = *(const short8*)(hb + l15 * 512 + (((kt * 4 + q) ^ l15) << 3));
        #pragma unroll
        for (int nt = 0; nt < 4; ++nt)
          acc[nt] = MFMA16(afr, wreg[kt][nt], acc[nt]);
      }
      #pragma unroll
      for (int kt = 12; kt < 16; ++kt) {
        short8 afr = *(const short8*)(hb + l15 * 512 + (((kt * 4 + q) ^ l15) << 3));
        #pragma unroll
        for (int nt = 0; nt < 4; ++nt) {
          short8 bfr = *(const short8*)(w_lds + (((kt - 12) * 32 + wave * 4 + nt) << 9) + lane * 8);
          acc[nt] = MFMA16(afr, bfr, acc[nt]);
        }
      }

      // epilogue: pre = acc + xp; CTRNN update in fp32; bf16 h -> other buffer
      #pragma unroll
      for (int nt = 0; nt < 4; ++nt) {
        int col = wave * 64 + nt * 16 + l15;
        int ck = col >> 3, cl = col & 7;
        float x0 = bf2f((short)(xq[nt].x & 0xffffu));
        float x1 = bf2f((short)(xq[nt].x >> 16));
        float x2 = bf2f((short)(xq[nt].y & 0xffffu));
        float x3 = bf2f((short)(xq[nt].y >> 16));
        float h0 = onem * hold[nt][0] + alpha * fmaxf(acc[nt][0] + x0, 0.f);
        float h1 = onem * hold[nt][1] + alpha * fmaxf(acc[nt][1] + x1, 0.f);
        float h2 = onem * hold[nt][2] + alpha * fmaxf(acc[nt][2] + x2, 0.f);
        float h3 = onem * hold[nt][3] + alpha * fmaxf(acc[nt][3] + x3, 0.f);
        hold[nt][0] = h0; hold[nt][1] = h1; hold[nt][2] = h2; hold[nt][3] = h3;
        unsigned u01 = cvt_pk_bf16(h0, h1);
        unsigned u23 = cvt_pk_bf16(h2, h3);
        int r0 = q * 4;
        hnb[(r0 + 0) * 512 + ((ck ^ (r0 + 0)) << 3) + cl] = (short)(u01 & 0xffffu);
        hnb[(r0 + 1) * 512 + ((ck ^ (r0 + 1)) << 3) + cl] = (short)(u01 >> 16);
        hnb[(r0 + 2) * 512 + ((ck ^ (r0 + 2)) << 3) + cl] = (short)(u23 & 0xffffu);
        hnb[(r0 + 3) * 512 + ((ck ^ (r0 + 3)) << 3) + cl] = (short)(u23 >> 16);
      }
      __syncthreads();  // single barrier per step (write buf != read buf)
      p ^= 1;
    }

    // tail: hs[chunk-1] + fp32 carry
    {
      const short* hb = hbuf + p * (16 * 512);
      int e = tid * 16;
      int row = e >> 9, c0 = (e & 511) >> 3;
      short8 v0 = *(const short8*)(hb + row * 512 + (((c0    ) ^ row) << 3));
      short8 v1 = *(const short8*)(hb + row * 512 + (((c0 + 1) ^ row) << 3));
      short* dst = hs + ((size_t)(chunk - 1) * BATCH + slab) * HID + e;
      *(short8*)(dst) = v0;
      *(short8*)(dst + 8) = v1;
    }
    #pragma unroll
    for (int nt = 0; nt < 4; ++nt) {
      int col = wave * 64 + nt * 16 + l15;
      #pragma unroll
      for (int r = 0; r < 4; ++r)
        h_carry[(size_t)(slab + q * 4 + r) * HID + col] = hold[nt][r];
    }

  } else if (bid - sb < nx) {
    // ================= xproj role: one timestep of chunk c+1 ================
    const int tt = bid - sb;
    const int cc = c + 1;
    short* xpw = (cc & 1) ? xp1 : xp0;
    const int t_abs = cc * chunk + tt;

    short8 bfr[4][4];  // ct = wave*4+i, kt 0..3
    #pragma unroll
    for (int i = 0; i < 4; ++i)
      #pragma unroll
      for (int kt = 0; kt < 4; ++kt)
        bfr[i][kt] = *(const short8*)(w_in_p + (((kt * 32 + wave * 4 + i) * 64 + lane) << 3));
    float brv[4];
    #pragma unroll
    for (int i = 0; i < 4; ++i) brv[i] = b_rec[(wave * 4 + i) * 16 + l15];

    for (int it = 0; it < 16; ++it) {
      const float* arow = inputs + ((size_t)t_abs * BATCH + it * 16 + l15) * INSZ + q * 8;
      short8 afr[4];
      #pragma unroll
      for (int kt = 0; kt < 4; ++kt) {
        short8 s;
        #pragma unroll
        for (int j = 0; j < 4; ++j) {
          unsigned u = cvt_pk_bf16(arow[kt * 32 + 2 * j], arow[kt * 32 + 2 * j + 1]);
          s[2 * j] = (short)(u & 0xffffu);
          s[2 * j + 1] = (short)(u >> 16);
        }
        afr[kt] = s;
      }
      floatx4 acc[4];
      #pragma unroll
      for (int i = 0; i < 4; ++i) acc[i] = (floatx4){0.f, 0.f, 0.f, 0.f};
      #pragma unroll
      for (int kt = 0; kt < 4; ++kt)
        #pragma unroll
        for (int i = 0; i < 4; ++i)
          acc[i] = MFMA16(afr[kt], bfr[i][kt], acc[i]);
      // store (acc + b_rec) as bf16 in fragment-linear layout: 8B/thread/ct
      #pragma unroll
      for (int i = 0; i < 4; ++i) {
        unsigned u01 = cvt_pk_bf16(acc[i][0] + brv[i], acc[i][1] + brv[i]);
        unsigned u23 = cvt_pk_bf16(acc[i][2] + brv[i], acc[i][3] + brv[i]);
        uint2 u; u.x = u01; u.y = u23;
        *(uint2*)(xpw + ((((size_t)tt * 16 + it) * 32 + wave * 4 + i) * 64 + lane) * 4) = u;
      }
    }

  } else {
    // ================= out role: one timestep of chunk c-1 ==================
    const int tt = bid - sb - nx;
    const int cc = c - 1;
    const short* hsr = (cc & 1) ? hs1 : hs0;
    short* al = (short*)smem + wave * (16 * 520);  // wave-private padded tile

    float bov[2] = { b_out[l15], b_out[16 + l15] };

    #pragma unroll
    for (int itm = 0; itm < 2; ++itm) {
      int mt = wave * 2 + itm;  // 16-row group within the timestep
      const short* src = hsr + ((size_t)tt * BATCH + mt * 16) * HID;
      #pragma unroll
      for (int r = 0; r < 16; ++r)
        *(short8*)(al + r * 520 + lane * 8) = *(const short8*)(src + r * 512 + lane * 8);
      // wave-private tile: in-wave DS ordering suffices, no barrier

      floatx4 acc2[2];
      acc2[0] = (floatx4){0.f, 0.f, 0.f, 0.f};
      acc2[1] = (floatx4){0.f, 0.f, 0.f, 0.f};
      #pragma unroll
      for (int kt = 0; kt < 16; ++kt) {
        short8 afr = *(const short8*)(al + l15 * 520 + kt * 32 + q * 8);
        short8 b0 = *(const short8*)(w_out_p + (((kt * 2 + 0) * 64 + lane) << 3));
        short8 b1 = *(const short8*)(w_out_p + (((kt * 2 + 1) * 64 + lane) << 3));
        acc2[0] = MFMA16(afr, b0, acc2[0]);
        acc2[1] = MFMA16(afr, b1, acc2[1]);
      }
      float* outp = out + ((size_t)(cc * chunk + tt) * BATCH + mt * 16) * OUTSZ;
      #pragma unroll
      for (int ot = 0; ot < 2; ++ot)
        #pragma unroll
        for (int r = 0; r < 4; ++r)
          outp[(size_t)(q * 4 + r) * OUTSZ + ot * 16 + l15] = acc2[ot][r] + bov[ot];
    }
  }
}

// ---------------------------------------------------------------------------
extern "C" void kernel_launch(void* const* d_in, const int* in_sizes, int n_in,
                              void* d_out, int out_size, void* d_ws, size_t ws_size,
                              hipStream_t stream) {
  const float* inputs = (const float*)d_in[0];  // [1024,256,128]
  const float* W_rec  = (const float*)d_in[1];  // [512,512]
  const float* W_in   = (const float*)d_in[2];  // [128,512]
  const float* b_rec  = (const float*)d_in[3];  // [512]
  const float* W_out  = (const float*)d_in[4];  // [512,32]
  const float* b_out  = (const float*)d_in[5];  // [32]
  float* out = (float*)d_out;                   // [1024,256,32]

  char* ws = (char*)d_ws;
  // fixed region (< 2 MB): packed weights + fp32 h carry
  short* w_rec_p = (short*)(ws);                       // 512 KB
  short* w_in_p  = (short*)(ws + 524288);              // 128 KB
  short* w_out_p = (short*)(ws + 655360);              //  32 KB
  float* h_carry = (float*)(ws + 688128);              // 512 KB
  const size_t fixed_end = 2u << 20;                   // 2 MB

  // double-buffered xp + hs: 4 buffers of chunk*256KB each -> 1 MB per step
  const size_t per_step = (size_t)BATCH * HID * 2 * 4;
  int chunk = T_STEPS;
  while (chunk > 1 && fixed_end + (size_t)chunk * per_step > ws_size) chunk >>= 1;
  if (fixed_end + (size_t)chunk * per_step > ws_size) return;  // ws too small
  const int nchunks = T_STEPS / chunk;

  const size_t buf = (size_t)chunk * BATCH * HID * 2;  // bytes per buffer
  short* xp0 = (short*)(ws + fixed_end);
  short* xp1 = (short*)(ws + fixed_end + buf);
  short* hs0 = (short*)(ws + fixed_end + 2 * buf);
  short* hs1 = (short*)(ws + fixed_end + 3 * buf);

  pack_kernel<<<1024, 256, 0, stream>>>(W_rec, W_in, W_out, w_rec_p, w_in_p, w_out_p);

  for (int c = -1; c <= nchunks; ++c) {
    int sb = (c >= 0 && c < nchunks) ? 16 : 0;
    int nx = (c + 1 >= 0 && c + 1 < nchunks) ? chunk : 0;
    int no = (c - 1 >= 0 && c - 1 < nchunks) ? chunk : 0;
    int grid = sb + nx + no;
    if (!grid) continue;
    fused_kernel<<<grid, 512, 0, stream>>>(inputs, w_rec_p, w_in_p, w_out_p,
        b_rec, b_out, xp0, xp1, hs0, hs1, h_carry, out, c, chunk, nchunks);
  }
}

// Round 6
// 3249.925 us; speedup vs baseline: 1.6719x; 1.5190x over previous
//
#include <hip/hip_runtime.h>

typedef __attribute__((ext_vector_type(8))) short short8;
typedef __attribute__((ext_vector_type(4))) float floatx4;

#define T_STEPS 1024
#define BATCH   256
#define INSZ    128
#define HID     512
#define OUTSZ   32

#define MFMA16(a,b,c) __builtin_amdgcn_mfma_f32_16x16x32_bf16((a),(b),(c),0,0,0)

// bf16 helpers (RNE)
static __device__ __forceinline__ short f2bf(float f) {
  unsigned int u = __float_as_uint(f);
  u += 0x7fffu + ((u >> 16) & 1u);
  return (short)(u >> 16);
}
static __device__ __forceinline__ float bf2f(short s) {
  return __uint_as_float(((unsigned int)(unsigned short)s) << 16);
}
// packed f32->bf16 (RNE), 1 inst for 2 values
static __device__ __forceinline__ unsigned cvt_pk_bf16(float lo, float hi) {
  unsigned r;
  asm("v_cvt_pk_bf16_f32 %0, %1, %2" : "=v"(r) : "v"(lo), "v"(hi));
  return r;
}

// ---------------------------------------------------------------------------
// Pack weights into MFMA B-fragment-linear bf16 layouts.
// B-frag for 16x16x32: lane = ((k%32)/8)*16 + (n%16), elem j = k%8.
// frag id = kt*NT + nt ; pos = (frag*64 + lane)*8 + j
// ---------------------------------------------------------------------------
__global__ __launch_bounds__(256) void pack_kernel(
    const float* __restrict__ W_rec, const float* __restrict__ W_in,
    const float* __restrict__ W_out,
    short* __restrict__ w_rec_p, short* __restrict__ w_in_p,
    short* __restrict__ w_out_p) {
  int i = blockIdx.x * 256 + threadIdx.x;  // 0..262143
  {
    // W_rec[n][k] used as B[k][n]  (h @ W_rec^T)
    int n = i >> 9, k = i & 511;
    int pos = ((((k >> 5) * 32 + (n >> 4)) * 64 + ((k >> 3) & 3) * 16 + (n & 15)) << 3) + (k & 7);
    w_rec_p[pos] = f2bf(W_rec[i]);
  }
  if (i < INSZ * HID) {
    int k = i >> 9, n = i & 511;  // W_in[k][n] used as B[k][n]
    int pos = ((((k >> 5) * 32 + (n >> 4)) * 64 + ((k >> 3) & 3) * 16 + (n & 15)) << 3) + (k & 7);
    w_in_p[pos] = f2bf(W_in[i]);
  }
  if (i < HID * OUTSZ) {
    int k = i >> 5, o = i & 31;   // W_out[k][o] used as B[k][o], NT=2
    int pos = ((((k >> 5) * 2 + (o >> 4)) * 64 + ((k >> 3) & 3) * 16 + (o & 15)) << 3) + (k & 7);
    w_out_p[pos] = f2bf(W_out[i]);
  }
}

// ---------------------------------------------------------------------------
// Fused kernel (512 thr = 8 waves), one launch per chunk phase c:
//   blocks [0,32)         : scan of chunk c. Block s: rows (s>>1)*16..+16,
//                           columns (s&1)*256..+256. Partner s^1 computes the
//                           other column half; halves exchanged per step via
//                           device-scope atomics + flag handshake.
//   blocks [32, 32+chunk) : xproj of chunk c+1 (one timestep per block)
//   remaining chunk blocks: out GEMM of chunk c-1
//
// Why the column split: the allocator hard-caps this kernel at 128 VGPRs
// (observed across 5 rounds vs every attribute/pin), so a full-column block
// (192-reg W tile) re-fetches W from L2 every step (~6000 cy/step = the scan
// bottleneck). Half columns -> W half = 128KB LDS (kt 8..15) + 64 VGPR
// (kt 0..7 x 2 ntiles); total demand ~115 <= 128 -> W truly resident.
// Exchange protocol: h halves published as relaxed agent-scope 8B atomic
// stores into parity-double-buffered slots (coherent point, no cache
// maintenance), then flag[s] = globalstep+1 after vmcnt drain + barrier.
// Parity reuse is safe: block rewrites parity P at step t+2 only after its
// step t+1 spin saw partner flag >= t+2, which implies partner finished step
// t and consumed P. Aux blocks never sync -> no circular wait; spin has an
// iteration cap so a bug fails (wrong data) instead of hanging.
// ---------------------------------------------------------------------------
__global__ __launch_bounds__(512, 1) void fused_kernel(
    const float* __restrict__ inputs,
    const short* __restrict__ w_rec_p, const short* __restrict__ w_in_p,
    const short* __restrict__ w_out_p,
    const float* __restrict__ b_rec, const float* __restrict__ b_out,
    short* __restrict__ xp0, short* __restrict__ xp1,
    short* __restrict__ hs0, short* __restrict__ hs1,
    float* __restrict__ h_carry, float* __restrict__ out,
    unsigned long long* __restrict__ xch, unsigned* __restrict__ flags,
    int c, int chunk, int nchunks) {
  __shared__ __align__(16) char smem[163840];  // scan 160K / out 8*16640
  const int tid  = threadIdx.x;
  const int wave = tid >> 6, lane = tid & 63;
  const int l15  = lane & 15, q = lane >> 4;

  const int sb = (c >= 0 && c < nchunks) ? 32 : 0;
  const int nx = (c + 1 < nchunks) ? chunk : 0;
  const int bid = blockIdx.x;

  if (bid < sb) {
    // ================= scan role ===========================================
    short* w_lds = (short*)smem;               // 128 KB: kt 8..15, own half
    short* hbuf  = (short*)(smem + 131072);    // 2 x 16KB double-buffered h
    const short* xp = (c & 1) ? xp1 : xp0;
    short* hs = (c & 1) ? hs1 : hs0;
    const int s    = bid;
    const int slab = s >> 1;                   // batch slab index
    const int ch   = s & 1;                    // column half
    const int ps   = s ^ 1;                    // partner block
    const int first = (c == 0);

    // registers: kt 0..7, own 2 col tiles per wave (64 VGPR)
    short8 wreg[8][2];
    #pragma unroll
    for (int kt = 0; kt < 8; ++kt)
      #pragma unroll
      for (int i = 0; i < 2; ++i) {
        int ct = (ch << 4) + wave * 2 + i;
        wreg[kt][i] = *(const short8*)(w_rec_p + (((kt * 32 + ct) * 64 + lane) << 3));
      }

    // LDS: kt 8..15, all 16 tiles of own half (contiguous 16KB per kt)
    for (int e = tid * 8; e < 8 * 16 * 512; e += 512 * 8) {
      int kt8 = e >> 13;          // 8192 shorts per kt
      int rest = e & 8191;
      *(short8*)(w_lds + e) =
          *(const short8*)(w_rec_p + ((8 + kt8) * 32 + (ch << 4)) * 512 + rest);
    }

    // hbuf[0] init: FULL h (both halves); hold regs: own half only
    #pragma unroll
    for (int g4 = 0; g4 < 4; ++g4) {
      int col = (wave * 4 + g4) * 16 + l15;
      int ck = col >> 3, cl = col & 7;
      #pragma unroll
      for (int r = 0; r < 4; ++r) {
        int row = q * 4 + r;
        float v = first ? 0.f : h_carry[(size_t)(slab * 16 + row) * HID + col];
        hbuf[row * 512 + ((ck ^ row) << 3) + cl] = f2bf(v);
      }
    }
    float hold[2][4];
    #pragma unroll
    for (int i = 0; i < 2; ++i) {
      int col = (ch << 8) + wave * 32 + i * 16 + l15;
      #pragma unroll
      for (int r = 0; r < 4; ++r)
        hold[i][r] = first ? 0.f : h_carry[(size_t)(slab * 16 + q * 4 + r) * HID + col];
    }

    const float alpha = (float)(0.1 / 100.0);
    const float onem  = (float)(1.0 - 0.1 / 100.0);

    __syncthreads();

    int p = 0;
    for (int t = 0; t < chunk; ++t) {
      const int g = c * chunk + t;                  // global step
      const short* hb = hbuf + p * (16 * 512);
      short* hnb = hbuf + (p ^ 1) * (16 * 512);

      // xp[t] own tiles, issued early (consumed in epilogue)
      uint2 xq[2];
      #pragma unroll
      for (int i = 0; i < 2; ++i)
        xq[i] = *(const uint2*)(xp + ((((size_t)t * 16 + slab) * 32 + (ch << 4) + wave * 2 + i) * 64 + lane) * 4);

      // hs[t-1] own half from stable buffer (overlaps MFMA)
      if (t > 0) {
        int e2 = tid * 16;                          // byte idx in own 8KB half
        int row = e2 >> 9, off = e2 & 511;
        int ck2 = (ch << 5) + (off >> 4);
        short8 v = *(const short8*)(hb + row * 512 + ((ck2 ^ row) << 3));
        *(short8*)(hs + ((size_t)(t - 1) * BATCH + slab * 16 + row) * HID + (ch << 8) + (off >> 1)) = v;
      }

      floatx4 acc[2];
      acc[0] = (floatx4){0.f, 0.f, 0.f, 0.f};
      acc[1] = (floatx4){0.f, 0.f, 0.f, 0.f};

      #pragma unroll
      for (int kt = 0; kt < 8; ++kt) {
        short8 afr = *(const short8*)(hb + l15 * 512 + (((kt * 4 + q) ^ l15) << 3));
        acc[0] = MFMA16(afr, wreg[kt][0], acc[0]);
        acc[1] = MFMA16(afr, wreg[kt][1], acc[1]);
      }
      #pragma unroll
      for (int kt = 8; kt < 16; ++kt) {
        short8 afr = *(const short8*)(hb + l15 * 512 + (((kt * 4 + q) ^ l15) << 3));
        #pragma unroll
        for (int i = 0; i < 2; ++i) {
          short8 bfr = *(const short8*)(w_lds + (kt - 8) * 8192 + (wave * 2 + i) * 512 + lane * 8);
          acc[i] = MFMA16(afr, bfr, acc[i]);
        }
      }

      // epilogue: CTRNN update, own half -> LDS + packed exchange payload
      unsigned long long pk[2];
      #pragma unroll
      for (int i = 0; i < 2; ++i) {
        int col = (ch << 8) + wave * 32 + i * 16 + l15;
        int ck = col >> 3, cl = col & 7;
        float x0 = bf2f((short)(xq[i].x & 0xffffu));
        float x1 = bf2f((short)(xq[i].x >> 16));
        float x2 = bf2f((short)(xq[i].y & 0xffffu));
        float x3 = bf2f((short)(xq[i].y >> 16));
        float h0 = onem * hold[i][0] + alpha * fmaxf(acc[i][0] + x0, 0.f);
        float h1 = onem * hold[i][1] + alpha * fmaxf(acc[i][1] + x1, 0.f);
        float h2 = onem * hold[i][2] + alpha * fmaxf(acc[i][2] + x2, 0.f);
        float h3 = onem * hold[i][3] + alpha * fmaxf(acc[i][3] + x3, 0.f);
        hold[i][0] = h0; hold[i][1] = h1; hold[i][2] = h2; hold[i][3] = h3;
        unsigned u01 = cvt_pk_bf16(h0, h1);
        unsigned u23 = cvt_pk_bf16(h2, h3);
        int r0 = q * 4;
        hnb[(r0 + 0) * 512 + ((ck ^ (r0 + 0)) << 3) + cl] = (short)(u01 & 0xffffu);
        hnb[(r0 + 1) * 512 + ((ck ^ (r0 + 1)) << 3) + cl] = (short)(u01 >> 16);
        hnb[(r0 + 2) * 512 + ((ck ^ (r0 + 2)) << 3) + cl] = (short)(u23 & 0xffffu);
        hnb[(r0 + 3) * 512 + ((ck ^ (r0 + 3)) << 3) + cl] = (short)(u23 >> 16);
        pk[i] = (unsigned long long)u01 | ((unsigned long long)u23 << 32);
      }

      if (t < chunk - 1) {
        // publish own half (parity slot) as device-scope atomics
        unsigned long long* xw = xch + (((size_t)((g + 1) & 1)) * 32 + s) * 1024;
        #pragma unroll
        for (int i = 0; i < 2; ++i) {
          int colLocal = wave * 32 + i * 16 + l15;
          __hip_atomic_store(&xw[colLocal * 4 + q], pk[i],
                             __ATOMIC_RELAXED, __HIP_MEMORY_SCOPE_AGENT);
        }
        asm volatile("s_waitcnt vmcnt(0)" ::: "memory");
        __syncthreads();                                     // all atomics out
        if (tid == 0) {
          __hip_atomic_store(&flags[s], (unsigned)(g + 1),
                             __ATOMIC_RELAXED, __HIP_MEMORY_SCOPE_AGENT);
          unsigned iters = 0;
          while (__hip_atomic_load(&flags[ps], __ATOMIC_RELAXED,
                                   __HIP_MEMORY_SCOPE_AGENT) < (unsigned)(g + 1)) {
            __builtin_amdgcn_s_sleep(1);
            if (++iters > (1u << 27)) break;                 // no-hang escape
          }
        }
        __syncthreads();                                     // partner ready
        // pull partner half into hnb
        const unsigned long long* xr = xch + (((size_t)((g + 1) & 1)) * 32 + ps) * 1024;
        #pragma unroll
        for (int j = 0; j < 2; ++j) {
          int sIdx = tid * 2 + j;
          unsigned long long v = __hip_atomic_load(&xr[sIdx], __ATOMIC_RELAXED,
                                                   __HIP_MEMORY_SCOPE_AGENT);
          int colLocal = sIdx >> 2, qq = sIdx & 3;
          int col = ((ch ^ 1) << 8) + colLocal;
          int ck = col >> 3, cl = col & 7;
          int r0 = qq * 4;
          hnb[(r0 + 0) * 512 + ((ck ^ (r0 + 0)) << 3) + cl] = (short)(v & 0xffffu);
          hnb[(r0 + 1) * 512 + ((ck ^ (r0 + 1)) << 3) + cl] = (short)((v >> 16) & 0xffffu);
          hnb[(r0 + 2) * 512 + ((ck ^ (r0 + 2)) << 3) + cl] = (short)((v >> 32) & 0xffffu);
          hnb[(r0 + 3) * 512 + ((ck ^ (r0 + 3)) << 3) + cl] = (short)(v >> 48);
        }
        __syncthreads();                                     // hnb complete
      } else {
        __syncthreads();  // last step: own writes visible for tail copy
      }
      p ^= 1;
    }

    // tail: hs[chunk-1] own half + fp32 carry own half
    {
      const short* hb = hbuf + p * (16 * 512);
      int e2 = tid * 16;
      int row = e2 >> 9, off = e2 & 511;
      int ck2 = (ch << 5) + (off >> 4);
      short8 v = *(const short8*)(hb + row * 512 + ((ck2 ^ row) << 3));
      *(short8*)(hs + ((size_t)(chunk - 1) * BATCH + slab * 16 + row) * HID + (ch << 8) + (off >> 1)) = v;
    }
    #pragma unroll
    for (int i = 0; i < 2; ++i) {
      int col = (ch << 8) + wave * 32 + i * 16 + l15;
      #pragma unroll
      for (int r = 0; r < 4; ++r)
        h_carry[(size_t)(slab * 16 + q * 4 + r) * HID + col] = hold[i][r];
    }

  } else if (bid - sb < nx) {
    // ================= xproj role: one timestep of chunk c+1 ================
    const int tt = bid - sb;
    const int cc = c + 1;
    short* xpw = (cc & 1) ? xp1 : xp0;
    const int t_abs = cc * chunk + tt;

    short8 bfr[4][4];  // ct = wave*4+i, kt 0..3
    #pragma unroll
    for (int i = 0; i < 4; ++i)
      #pragma unroll
      for (int kt = 0; kt < 4; ++kt)
        bfr[i][kt] = *(const short8*)(w_in_p + (((kt * 32 + wave * 4 + i) * 64 + lane) << 3));
    float brv[4];
    #pragma unroll
    for (int i = 0; i < 4; ++i) brv[i] = b_rec[(wave * 4 + i) * 16 + l15];

    for (int it = 0; it < 16; ++it) {
      const float* arow = inputs + ((size_t)t_abs * BATCH + it * 16 + l15) * INSZ + q * 8;
      short8 afr[4];
      #pragma unroll
      for (int kt = 0; kt < 4; ++kt) {
        short8 sv;
        #pragma unroll
        for (int j = 0; j < 4; ++j) {
          unsigned u = cvt_pk_bf16(arow[kt * 32 + 2 * j], arow[kt * 32 + 2 * j + 1]);
          sv[2 * j] = (short)(u & 0xffffu);
          sv[2 * j + 1] = (short)(u >> 16);
        }
        afr[kt] = sv;
      }
      floatx4 acc[4];
      #pragma unroll
      for (int i = 0; i < 4; ++i) acc[i] = (floatx4){0.f, 0.f, 0.f, 0.f};
      #pragma unroll
      for (int kt = 0; kt < 4; ++kt)
        #pragma unroll
        for (int i = 0; i < 4; ++i)
          acc[i] = MFMA16(afr[kt], bfr[i][kt], acc[i]);
      #pragma unroll
      for (int i = 0; i < 4; ++i) {
        unsigned u01 = cvt_pk_bf16(acc[i][0] + brv[i], acc[i][1] + brv[i]);
        unsigned u23 = cvt_pk_bf16(acc[i][2] + brv[i], acc[i][3] + brv[i]);
        uint2 u; u.x = u01; u.y = u23;
        *(uint2*)(xpw + ((((size_t)tt * 16 + it) * 32 + wave * 4 + i) * 64 + lane) * 4) = u;
      }
    }

  } else {
    // ================= out role: one timestep of chunk c-1 ==================
    const int tt = bid - sb - nx;
    const int cc = c - 1;
    const short* hsr = (cc & 1) ? hs1 : hs0;
    short* al = (short*)smem + wave * (16 * 520);  // wave-private padded tile

    float bov[2] = { b_out[l15], b_out[16 + l15] };

    #pragma unroll
    for (int itm = 0; itm < 2; ++itm) {
      int mt = wave * 2 + itm;
      const short* src = hsr + ((size_t)tt * BATCH + mt * 16) * HID;
      #pragma unroll
      for (int r = 0; r < 16; ++r)
        *(short8*)(al + r * 520 + lane * 8) = *(const short8*)(src + r * 512 + lane * 8);
      // wave-private tile: in-wave DS ordering suffices, no barrier

      floatx4 acc2[2];
      acc2[0] = (floatx4){0.f, 0.f, 0.f, 0.f};
      acc2[1] = (floatx4){0.f, 0.f, 0.f, 0.f};
      #pragma unroll
      for (int kt = 0; kt < 16; ++kt) {
        short8 afr = *(const short8*)(al + l15 * 520 + kt * 32 + q * 8);
        short8 b0 = *(const short8*)(w_out_p + (((kt * 2 + 0) * 64 + lane) << 3));
        short8 b1 = *(const short8*)(w_out_p + (((kt * 2 + 1) * 64 + lane) << 3));
        acc2[0] = MFMA16(afr, b0, acc2[0]);
        acc2[1] = MFMA16(afr, b1, acc2[1]);
      }
      float* outp = out + ((size_t)(cc * chunk + tt) * BATCH + mt * 16) * OUTSZ;
      #pragma unroll
      for (int ot = 0; ot < 2; ++ot)
        #pragma unroll
        for (int r = 0; r < 4; ++r)
          outp[(size_t)(q * 4 + r) * OUTSZ + ot * 16 + l15] = acc2[ot][r] + bov[ot];
    }
  }
}

// ---------------------------------------------------------------------------
extern "C" void kernel_launch(void* const* d_in, const int* in_sizes, int n_in,
                              void* d_out, int out_size, void* d_ws, size_t ws_size,
                              hipStream_t stream) {
  const float* inputs = (const float*)d_in[0];  // [1024,256,128]
  const float* W_rec  = (const float*)d_in[1];  // [512,512]
  const float* W_in   = (const float*)d_in[2];  // [128,512]
  const float* b_rec  = (const float*)d_in[3];  // [512]
  const float* W_out  = (const float*)d_in[4];  // [512,32]
  const float* b_out  = (const float*)d_in[5];  // [32]
  float* out = (float*)d_out;                   // [1024,256,32]

  char* ws = (char*)d_ws;
  // fixed region (< 2 MB): packed weights + fp32 carry + exchange + flags
  short* w_rec_p = (short*)(ws);                        // 512 KB
  short* w_in_p  = (short*)(ws + 524288);               // 128 KB
  short* w_out_p = (short*)(ws + 655360);               //  32 KB
  float* h_carry = (float*)(ws + 688128);               // 512 KB
  unsigned long long* xch = (unsigned long long*)(ws + 1200128);  // 512 KB
  unsigned* flags = (unsigned*)(ws + 1724416);          // 128 B
  const size_t fixed_end = 2u << 20;                    // 2 MB

  // double-buffered xp + hs: 4 buffers of chunk*256KB each
  const size_t per_step = (size_t)BATCH * HID * 2 * 4;
  int chunk = T_STEPS;
  while (chunk > 1 && fixed_end + (size_t)chunk * per_step > ws_size) chunk >>= 1;
  if (fixed_end + (size_t)chunk * per_step > ws_size) return;  // ws too small
  const int nchunks = T_STEPS / chunk;

  const size_t buf = (size_t)chunk * BATCH * HID * 2;  // bytes per buffer
  short* xp0 = (short*)(ws + fixed_end);
  short* xp1 = (short*)(ws + fixed_end + buf);
  short* hs0 = (short*)(ws + fixed_end + 2 * buf);
  short* hs1 = (short*)(ws + fixed_end + 3 * buf);

  hipMemsetAsync(flags, 0, 128, stream);
  pack_kernel<<<1024, 256, 0, stream>>>(W_rec, W_in, W_out, w_rec_p, w_in_p, w_out_p);

  for (int c = -1; c <= nchunks; ++c) {
    int sb = (c >= 0 && c < nchunks) ? 32 : 0;
    int nx = (c + 1 >= 0 && c + 1 < nchunks) ? chunk : 0;
    int no = (c - 1 >= 0 && c - 1 < nchunks) ? chunk : 0;
    int grid = sb + nx + no;
    if (!grid) continue;
    fused_kernel<<<grid, 512, 0, stream>>>(inputs, w_rec_p, w_in_p, w_out_p,
        b_rec, b_out, xp0, xp1, hs0, hs1, h_carry, out, xch, flags,
        c, chunk, nchunks);
  }
}